// Round 13
// baseline (210.971 us; speedup 1.0000x reference)
//
#include <hip/hip_runtime.h>

#define BB 8
#define NN 8192
#define NPOINT 2048
#define NSAMPLE 64
#define CIN 64
#define RADIUS 0.2f
#define R2 (RADIUS * RADIUS)

// d_out layout (flat floats, reference return order)
#define OFF_NEWXYZ 0
#define OFF_FEAT (BB * NPOINT * 3)
#define OFF_INDS (OFF_FEAT + BB * NPOINT * 128)
#define OFF_IDX (OFF_INDS + BB * NPOINT)

typedef _Float16 half8 __attribute__((ext_vector_type(8)));
typedef _Float16 half4 __attribute__((ext_vector_type(4)));
typedef __fp16 f16x2 __attribute__((ext_vector_type(2)));
typedef float floatx16 __attribute__((ext_vector_type(16)));

// Per-wave LDS slice (halves). P0=88, P1=72 (R6-proven; no swizzle, no extra
// LDS — 40960B = exactly 4 blocks/CU).
#define P0 88
#define P1 72
#define X_LOC 0
#define H_LOC (64 * P0)                 // 5632
#define XH_WAVE (64 * P0 + 64 * P1)     // 10240 halves = 20480 B per wave
#define WT0_S 0
#define WT1_S (64 * P0)
#define WT2_S (64 * P0 + 64 * P1)       // fits in 2*XH_WAVE

#define QPW 8  // queries per wave; 1024 blocks = 4 blocks/CU, no tail

// ---------------------------------------------------------------------------
// Kernel 1: ball query, two queries per wave (pair shares a batch), 512
// candidates per iteration with alternating register sets (no rotate movs,
// half the loop overhead — matters for the full-scan tail: corner queries
// with <64 in-radius points scan all 8192 candidates).
// Distance formula must stay qq + nn - 2*dot (reference rounding).
// ---------------------------------------------------------------------------
__global__ __launch_bounds__(256) void ballq_kernel(
    const float* __restrict__ xyz, const int* __restrict__ inds,
    float* __restrict__ out) {
  __shared__ int sidx[4][2][NSAMPLE];  // 2 KB: 4 waves x 2 queries
  const int wave = (blockIdx.x * 256 + threadIdx.x) >> 6;
  const int lane = threadIdx.x & 63;
  const int wid = threadIdx.x >> 6;
  const int q0 = wave * 2, q1 = q0 + 1;
  const int b = q0 >> 11;  // NPOINT = 2048; pair shares batch

  const float* xb = xyz + (size_t)b * NN * 3;
  const int i0 = inds[q0], i1 = inds[q1];
  const float c0x = xb[i0 * 3 + 0], c0y = xb[i0 * 3 + 1], c0z = xb[i0 * 3 + 2];
  const float c1x = xb[i1 * 3 + 0], c1y = xb[i1 * 3 + 1], c1z = xb[i1 * 3 + 2];

  if (lane < 2) {
    const int qq_ = lane ? q1 : q0;
    const int ii = lane ? i1 : i0;
    out[OFF_NEWXYZ + (size_t)qq_ * 3 + 0] = lane ? c1x : c0x;
    out[OFF_NEWXYZ + (size_t)qq_ * 3 + 1] = lane ? c1y : c0y;
    out[OFF_NEWXYZ + (size_t)qq_ * 3 + 2] = lane ? c1z : c0z;
    out[OFF_INDS + qq_] = (float)ii;
  }

  const float qq0 = c0x * c0x + c0y * c0y + c0z * c0z;
  const float qq1 = c1x * c1x + c1y * c1y + c1z * c1z;

  int cnt0 = 0, cnt1 = 0;
  float Ax[4], Ay[4], Az[4], Bx[4], By[4], Bz[4];
#pragma unroll
  for (int k = 0; k < 4; ++k) {
    const float* p = xb + (size_t)(k * 64 + lane) * 3;
    Ax[k] = p[0]; Ay[k] = p[1]; Az[k] = p[2];
    const float* p2 = xb + (size_t)(256 + k * 64 + lane) * 3;
    Bx[k] = p2[0]; By[k] = p2[1]; Bz[k] = p2[2];
  }

#define BALLQ_STEP(PX, PY, PZ, JBASE, K)                                     \
  {                                                                          \
    const int j = (JBASE) + (K)*64 + lane;                                   \
    const float nn_ =                                                        \
        PX[K] * PX[K] + PY[K] * PY[K] + PZ[K] * PZ[K];                       \
    const float dot0 = c0x * PX[K] + c0y * PY[K] + c0z * PZ[K];              \
    const float dot1 = c1x * PX[K] + c1y * PY[K] + c1z * PZ[K];              \
    const bool hit0 = (qq0 + nn_ - 2.0f * dot0) < R2;                        \
    const bool hit1 = (qq1 + nn_ - 2.0f * dot1) < R2;                        \
    const unsigned long long m0 = __ballot(hit0);                            \
    const unsigned long long m1 = __ballot(hit1);                            \
    if (hit0) {                                                              \
      const int pos = cnt0 + (int)__popcll(m0 & ((1ull << lane) - 1ull));    \
      if (pos < NSAMPLE) sidx[wid][0][pos] = j;                              \
    }                                                                        \
    if (hit1) {                                                              \
      const int pos = cnt1 + (int)__popcll(m1 & ((1ull << lane) - 1ull));    \
      if (pos < NSAMPLE) sidx[wid][1][pos] = j;                              \
    }                                                                        \
    cnt0 += (int)__popcll(m0);                                               \
    cnt1 += (int)__popcll(m1);                                               \
  }

  for (int j0 = 0; j0 < NN; j0 += 512) {
    // process A-set (pts j0..j0+255), then refill A from j0+512
#pragma unroll
    for (int k = 0; k < 4; ++k) BALLQ_STEP(Ax, Ay, Az, j0, k)
    if (j0 + 512 < NN) {
#pragma unroll
      for (int k = 0; k < 4; ++k) {
        const float* p = xb + (size_t)(j0 + 512 + k * 64 + lane) * 3;
        Ax[k] = p[0]; Ay[k] = p[1]; Az[k] = p[2];
      }
    }
    // process B-set (pts j0+256..j0+511), then refill B from j0+768
#pragma unroll
    for (int k = 0; k < 4; ++k) BALLQ_STEP(Bx, By, Bz, j0 + 256, k)
    if (j0 + 768 < NN) {
#pragma unroll
      for (int k = 0; k < 4; ++k) {
        const float* p = xb + (size_t)(j0 + 768 + k * 64 + lane) * 3;
        Bx[k] = p[0]; By[k] = p[1]; Bz[k] = p[2];
      }
    }
    if (cnt0 >= NSAMPLE && cnt1 >= NSAMPLE) break;
  }
#undef BALLQ_STEP

  // Pad with first hit (center always hits itself -> cnt >= 1). Same-wave DS
  // ops are in-order: reads below see the scatter writes without a barrier.
  const int v0 = sidx[wid][0][lane < cnt0 ? lane : 0];
  out[OFF_IDX + (size_t)q0 * NSAMPLE + lane] = (float)v0;
  const int v1 = sidx[wid][1][lane < cnt1 ? lane : 0];
  out[OFF_IDX + (size_t)q1 * NSAMPLE + lane] = (float)v1;
}

// ---------------------------------------------------------------------------
// Kernel 2: barrier-free MFMA MLP (R6 core) + split-gather cross-query
// pipeline: query qi+1's 16 float4 feature loads are issued in two 32-reg
// halves (after L0 and after L1) and staged into xbuf right after L2's h1a
// reads free it -> gather latency hidden behind ~2 layers of compute, peak
// liveness ~240 VGPR (< 256 budget; R10's single 64-reg prefetch spilled).
// Same-wave DS ordering makes the stage-after-read safe without barriers.
// ---------------------------------------------------------------------------
__global__ __launch_bounds__(128, 2) void mlp_mfma(
    const float* __restrict__ xyz, const float* __restrict__ features,
    const int* __restrict__ inds,
    const float* __restrict__ w0, const float* __restrict__ s0,
    const float* __restrict__ t0, const float* __restrict__ w1,
    const float* __restrict__ s1, const float* __restrict__ t1,
    const float* __restrict__ w2, const float* __restrict__ s2,
    const float* __restrict__ t2, float* __restrict__ out) {
  __shared__ _Float16 sm[2 * XH_WAVE];  // 40960 B -> 4 blocks/CU, 8 waves/CU
  const int tid = threadIdx.x;
  const int w = tid >> 6;
  const int l = tid & 63;
  const int l31 = l & 31;
  const int h5 = l >> 5;
  const int koff = h5 * 8;  // fragment k-offset in halves

  // ---- stage folded weights into fragment-layout LDS (block-wide, once) ----
  {
    const int d = tid >> 1, hf = tid & 1;
    const float sd0 = s0[d], td0 = t0[d], sd1 = s1[d];
#pragma unroll
    for (int j = 0; j < 44; ++j) {
      const int c = hf * 44 + j;
      float v = 0.0f;
      if (c < 64) v = w0[(3 + c) * 64 + d] * sd0;        // feature channels
      else if (c < 67) v = w0[(c - 64) * 64 + d] * sd0;  // xyz channels
      else if (c == 67) v = td0;                         // bias channel
      sm[WT0_S + d * P0 + c] = (_Float16)v;
    }
#pragma unroll
    for (int j = 0; j < 32; ++j) {
      const int c = hf * 32 + j;
      sm[WT1_S + d * P1 + c] = (_Float16)(w1[c * 64 + d] * sd1);
    }
    const int ch = tid;  // 0..127
    const float sch = s2[ch];
#pragma unroll
    for (int c = 0; c < 64; ++c)
      sm[WT2_S + ch * P1 + c] = (_Float16)(w2[c * 128 + ch] * sch);
  }
  __syncthreads();

  // ---- hoist weight fragments + t vectors into registers ----
  half8 b0f[2][5], b1f[2][4], b2f[4][4];
#pragma unroll
  for (int nt = 0; nt < 2; ++nt)
#pragma unroll
    for (int ks = 0; ks < 5; ++ks)
      b0f[nt][ks] =
          *(const half8*)&sm[WT0_S + (nt * 32 + l31) * P0 + ks * 16 + koff];
#pragma unroll
  for (int nt = 0; nt < 2; ++nt)
#pragma unroll
    for (int ks = 0; ks < 4; ++ks)
      b1f[nt][ks] =
          *(const half8*)&sm[WT1_S + (nt * 32 + l31) * P1 + ks * 16 + koff];
#pragma unroll
  for (int ct = 0; ct < 4; ++ct)
#pragma unroll
    for (int ks = 0; ks < 4; ++ks)
      b2f[ct][ks] =
          *(const half8*)&sm[WT2_S + (ct * 32 + l31) * P1 + ks * 16 + koff];
  const float t1v0 = t1[l31];
  const float t1v1 = t1[32 + l31];
  float t2v[4];
#pragma unroll
  for (int ct = 0; ct < 4; ++ct) t2v[ct] = t2[ct * 32 + l31];
  __syncthreads();  // all fragment reads done before slices overwrite region

  _Float16* xbuf = sm + w * XH_WAVE + X_LOC;
  _Float16* hbuf = sm + w * XH_WAVE + H_LOC;
  // zero X K-pad halves 72..79 once (64..71 rewritten per query)
  {
    half8 z = {};
    *(half8*)&xbuf[l * P0 + 72] = z;
  }

  const int wq0 = (blockIdx.x * 2 + w) * QPW;
  const int b = wq0 >> 11;  // all QPW queries share one batch
  const float* xb = xyz + (size_t)b * NN * 3;
  const float* fbase = features + (size_t)b * NN * CIN;

  // ---- prologue: fully gather + stage X for query wq0 ----
  {
    const int idx0 = (int)out[OFF_IDX + (size_t)wq0 * NSAMPLE + l];
    const int ind0 = inds[wq0];
    const float cx = xb[ind0 * 3 + 0], cy = xb[ind0 * 3 + 1],
                cz = xb[ind0 * 3 + 2];
    const float px = xb[idx0 * 3 + 0], py = xb[idx0 * 3 + 1],
                pz = xb[idx0 * 3 + 2];
    float4 g[16];
#pragma unroll
    for (int i = 0; i < 16; ++i) {
      const int s = (l >> 2) + 16 * (i & 3);
      const int c = (l & 3) + 4 * (i >> 2);
      const int si = __shfl(idx0, s, 64);
      g[i] = *(const float4*)(fbase + (size_t)si * CIN + 4 * c);
    }
#pragma unroll
    for (int i = 0; i < 16; ++i) {
      const int s = (l >> 2) + 16 * (i & 3);
      const int c = (l & 3) + 4 * (i >> 2);
      union { half4 v; f16x2 p[2]; } hv;
      hv.p[0] = __builtin_amdgcn_cvt_pkrtz(g[i].x, g[i].y);
      hv.p[1] = __builtin_amdgcn_cvt_pkrtz(g[i].z, g[i].w);
      *(half4*)&xbuf[s * P0 + 4 * c] = hv.v;
    }
    union { half8 v; f16x2 p[4]; } xv;
    xv.p[0] = __builtin_amdgcn_cvt_pkrtz((px - cx) * 5.0f, (py - cy) * 5.0f);
    xv.p[1] = __builtin_amdgcn_cvt_pkrtz((pz - cz) * 5.0f, 1.0f);  // bias
    xv.p[2] = __builtin_amdgcn_cvt_pkrtz(0.0f, 0.0f);
    xv.p[3] = __builtin_amdgcn_cvt_pkrtz(0.0f, 0.0f);
    *(half8*)&xbuf[l * P0 + 64] = xv.v;
  }

#pragma unroll 1
  for (int qi = 0; qi < QPW; ++qi) {
    const int q = wq0 + qi;
    const int nq = (qi + 1 < QPW) ? q + 1 : q;  // clamp: redundant restage ok

    // issue next query's idx + center-index loads (needed after L0)
    const float fni = out[OFF_IDX + (size_t)nq * NSAMPLE + l];
    const int nindv = inds[nq];

    // ---- L0: H0 = relu(X @ W0' + t0) (K=80, bias via channel 67) ----
    {
      half8 xa[2][5];
#pragma unroll
      for (int st = 0; st < 2; ++st)
#pragma unroll
        for (int ks = 0; ks < 5; ++ks)
          xa[st][ks] =
              *(const half8*)&xbuf[(st * 32 + l31) * P0 + ks * 16 + koff];
#pragma unroll
      for (int nt = 0; nt < 2; ++nt)
#pragma unroll
        for (int st = 0; st < 2; ++st) {
          floatx16 acc;
#pragma unroll
          for (int i = 0; i < 16; ++i) acc[i] = 0.0f;
#pragma unroll
          for (int ks = 0; ks < 5; ++ks)
            acc = __builtin_amdgcn_mfma_f32_32x32x16_f16(xa[st][ks],
                                                         b0f[nt][ks], acc,
                                                         0, 0, 0);
#pragma unroll
          for (int reg = 0; reg < 16; ++reg) {
            const int row = st * 32 + (reg & 3) + 8 * (reg >> 2) + 4 * h5;
            hbuf[row * P1 + nt * 32 + l31] = (_Float16)fmaxf(acc[reg], 0.0f);
          }
        }
    }

    // ---- issue next query's gather, first half (cols 0..31) + bias xyz ----
    const int nidxs = (int)fni;
    float4 g1[8];
#pragma unroll
    for (int i = 0; i < 8; ++i) {
      const int s = (l >> 2) + 16 * (i & 3);
      const int c = (l & 3) + 4 * (i >> 2);
      const int si = __shfl(nidxs, s, 64);
      g1[i] = *(const float4*)(fbase + (size_t)si * CIN + 4 * c);
    }
    const float ncx = xb[nindv * 3 + 0];
    const float ncy = xb[nindv * 3 + 1];
    const float ncz = xb[nindv * 3 + 2];
    const float nppx = xb[nidxs * 3 + 0];
    const float nppy = xb[nidxs * 3 + 1];
    const float nppz = xb[nidxs * 3 + 2];

    // ---- L1: H1 = relu(H0 @ W1' + t1), written into xbuf cols 0..63 ----
    {
      half8 ha[2][4];
#pragma unroll
      for (int st = 0; st < 2; ++st)
#pragma unroll
        for (int ks = 0; ks < 4; ++ks)
          ha[st][ks] =
              *(const half8*)&hbuf[(st * 32 + l31) * P1 + ks * 16 + koff];
#pragma unroll
      for (int nt = 0; nt < 2; ++nt) {
        const float tt = nt ? t1v1 : t1v0;
#pragma unroll
        for (int st = 0; st < 2; ++st) {
          floatx16 acc;
#pragma unroll
          for (int i = 0; i < 16; ++i) acc[i] = 0.0f;
#pragma unroll
          for (int ks = 0; ks < 4; ++ks)
            acc = __builtin_amdgcn_mfma_f32_32x32x16_f16(ha[st][ks],
                                                         b1f[nt][ks], acc,
                                                         0, 0, 0);
#pragma unroll
          for (int reg = 0; reg < 16; ++reg) {
            const int row = st * 32 + (reg & 3) + 8 * (reg >> 2) + 4 * h5;
            xbuf[row * P0 + nt * 32 + l31] =
                (_Float16)fmaxf(acc[reg] + tt, 0.0f);
          }
        }
      }
    }

    // ---- issue next query's gather, second half (cols 32..63) ----
    float4 g2[8];
#pragma unroll
    for (int i = 8; i < 16; ++i) {
      const int s = (l >> 2) + 16 * (i & 3);
      const int c = (l & 3) + 4 * (i >> 2);
      const int si = __shfl(nidxs, s, 64);
      g2[i - 8] = *(const float4*)(fbase + (size_t)si * CIN + 4 * c);
    }

    // ---- L2: read h1a, then restage X for nq, then MFMA + maxpool ----
    {
      half8 h1a[2][4];
#pragma unroll
      for (int st = 0; st < 2; ++st)
#pragma unroll
        for (int ks = 0; ks < 4; ++ks)
          h1a[st][ks] =
              *(const half8*)&xbuf[(st * 32 + l31) * P0 + ks * 16 + koff];

      // xbuf's H1 is now in registers -> stage next query's X (source order
      // after the reads; same-wave DS ops are in-order so no barrier needed)
#pragma unroll
      for (int i = 0; i < 8; ++i) {
        const int s = (l >> 2) + 16 * (i & 3);
        const int c = (l & 3) + 4 * (i >> 2);
        union { half4 v; f16x2 p[2]; } hv;
        hv.p[0] = __builtin_amdgcn_cvt_pkrtz(g1[i].x, g1[i].y);
        hv.p[1] = __builtin_amdgcn_cvt_pkrtz(g1[i].z, g1[i].w);
        *(half4*)&xbuf[s * P0 + 4 * c] = hv.v;
      }
#pragma unroll
      for (int i = 8; i < 16; ++i) {
        const int s = (l >> 2) + 16 * (i & 3);
        const int c = (l & 3) + 4 * (i >> 2);
        union { half4 v; f16x2 p[2]; } hv;
        hv.p[0] = __builtin_amdgcn_cvt_pkrtz(g2[i - 8].x, g2[i - 8].y);
        hv.p[1] = __builtin_amdgcn_cvt_pkrtz(g2[i - 8].z, g2[i - 8].w);
        *(half4*)&xbuf[s * P0 + 4 * c] = hv.v;
      }
      {
        union { half8 v; f16x2 p[4]; } xv;
        xv.p[0] = __builtin_amdgcn_cvt_pkrtz((nppx - ncx) * 5.0f,
                                             (nppy - ncy) * 5.0f);
        xv.p[1] = __builtin_amdgcn_cvt_pkrtz((nppz - ncz) * 5.0f, 1.0f);
        xv.p[2] = __builtin_amdgcn_cvt_pkrtz(0.0f, 0.0f);
        xv.p[3] = __builtin_amdgcn_cvt_pkrtz(0.0f, 0.0f);
        *(half8*)&xbuf[l * P0 + 64] = xv.v;
      }

#pragma unroll
      for (int ct = 0; ct < 4; ++ct) {
        floatx16 aA, aB;
#pragma unroll
        for (int i = 0; i < 16; ++i) {
          aA[i] = 0.0f;
          aB[i] = 0.0f;
        }
#pragma unroll
        for (int ks = 0; ks < 4; ++ks) {
          aA = __builtin_amdgcn_mfma_f32_32x32x16_f16(h1a[0][ks], b2f[ct][ks],
                                                      aA, 0, 0, 0);
          aB = __builtin_amdgcn_mfma_f32_32x32x16_f16(h1a[1][ks], b2f[ct][ks],
                                                      aB, 0, 0, 0);
        }
        float m = fmaxf(aA[0], aB[0]);
#pragma unroll
        for (int i = 1; i < 16; ++i) m = fmaxf(m, fmaxf(aA[i], aB[i]));
        float v = fmaxf(m + t2v[ct], 0.0f);  // relu(max+t) == max(relu(+t))
        v = fmaxf(v, __shfl_xor(v, 32, 64));  // merge complementary row halves
        if (l < 32) out[OFF_FEAT + (size_t)q * 128 + ct * 32 + l] = v;
      }
    }
  }
}

extern "C" void kernel_launch(void* const* d_in, const int* in_sizes, int n_in,
                              void* d_out, int out_size, void* d_ws,
                              size_t ws_size, hipStream_t stream) {
  const float* xyz = (const float*)d_in[0];
  const float* features = (const float*)d_in[1];
  const int* inds = (const int*)d_in[2];
  const float* w0 = (const float*)d_in[3];
  const float* s0 = (const float*)d_in[4];
  const float* t0 = (const float*)d_in[5];
  const float* w1 = (const float*)d_in[6];
  const float* s1 = (const float*)d_in[7];
  const float* t1 = (const float*)d_in[8];
  const float* w2 = (const float*)d_in[9];
  const float* s2 = (const float*)d_in[10];
  const float* t2 = (const float*)d_in[11];
  float* out = (float*)d_out;

  const int nquery = BB * NPOINT;  // 16384
  // ballq: 2 queries per wave -> 8192 waves -> 2048 blocks
  ballq_kernel<<<nquery / 8, 256, 0, stream>>>(xyz, inds, out);
  // mlp: 2 waves/block * QPW queries each -> 1024 blocks = 4 blocks/CU
  mlp_mfma<<<nquery / (2 * QPW), 128, 0, stream>>>(
      xyz, features, inds, w0, s0, t0, w1, s1, t1, w2, s2, t2, out);
}

// Round 14
// 185.055 us; speedup vs baseline: 1.1400x; 1.1400x over previous
//
#include <hip/hip_runtime.h>

#define BB 8
#define NN 8192
#define NPOINT 2048
#define NSAMPLE 64
#define CIN 64
#define RADIUS 0.2f
#define R2 (RADIUS * RADIUS)

// d_out layout (flat floats, reference return order)
#define OFF_NEWXYZ 0
#define OFF_FEAT (BB * NPOINT * 3)
#define OFF_INDS (OFF_FEAT + BB * NPOINT * 128)
#define OFF_IDX (OFF_INDS + BB * NPOINT)

typedef _Float16 half8 __attribute__((ext_vector_type(8)));
typedef _Float16 half4 __attribute__((ext_vector_type(4)));
typedef __fp16 f16x2 __attribute__((ext_vector_type(2)));
typedef float floatx16 __attribute__((ext_vector_type(16)));

// Single ping-pong buffer per wave: X (64x88), then H0 (64x64 @ pitch 88),
// then H1 — each phase's reads complete (into registers) before the next
// phase's writes issue, and per-wave DS ops execute in order, so one buffer
// suffices. 11264 B/wave -> 22528 B/block -> 7 blocks/CU = 14 waves/CU
// (vs 8 at R12's 40960 B). P0=88 proven near-conflict-free (R6).
#define P0 88
#define XW (64 * P0)  // 5632 halves per wave slice
// weight staging (block-shared, two phases, overlaps the wave slices):
#define WT0_S 0       // phase A: pitch 88, 64 rows -> 5632
#define WT1_S XW      // phase A: pitch 72, 64 rows -> 4608 (ends 10240<11264)
#define WT2_S 0       // phase B: pitch 72, 128 rows -> 9216 < 11264

#define QPW 4  // queries per wave -> 2048 blocks = 8 blocks/CU issued

// ---------------------------------------------------------------------------
// Kernel 1: ball query (R12 verbatim): two queries per wave (pair shares a
// batch), one point stream feeds two independent distance/ballot chains,
// LDS scatter + coalesced store. High occupancy hides the serial chain —
// keep separate from the MLP kernel (R9 fusion regression).
// Distance formula must stay qq + nn - 2*dot (reference rounding).
// ---------------------------------------------------------------------------
__global__ __launch_bounds__(256) void ballq_kernel(
    const float* __restrict__ xyz, const int* __restrict__ inds,
    float* __restrict__ out) {
  __shared__ int sidx[4][2][NSAMPLE];  // 2 KB: 4 waves x 2 queries
  const int wave = (blockIdx.x * 256 + threadIdx.x) >> 6;
  const int lane = threadIdx.x & 63;
  const int wid = threadIdx.x >> 6;
  const int q0 = wave * 2, q1 = q0 + 1;
  const int b = q0 >> 11;  // NPOINT = 2048; pair shares batch

  const float* xb = xyz + (size_t)b * NN * 3;
  const int i0 = inds[q0], i1 = inds[q1];
  const float c0x = xb[i0 * 3 + 0], c0y = xb[i0 * 3 + 1], c0z = xb[i0 * 3 + 2];
  const float c1x = xb[i1 * 3 + 0], c1y = xb[i1 * 3 + 1], c1z = xb[i1 * 3 + 2];

  if (lane < 2) {
    const int qq_ = lane ? q1 : q0;
    const int ii = lane ? i1 : i0;
    out[OFF_NEWXYZ + (size_t)qq_ * 3 + 0] = lane ? c1x : c0x;
    out[OFF_NEWXYZ + (size_t)qq_ * 3 + 1] = lane ? c1y : c0y;
    out[OFF_NEWXYZ + (size_t)qq_ * 3 + 2] = lane ? c1z : c0z;
    out[OFF_INDS + qq_] = (float)ii;
  }

  const float qq0 = c0x * c0x + c0y * c0y + c0z * c0z;
  const float qq1 = c1x * c1x + c1y * c1y + c1z * c1z;

  int cnt0 = 0, cnt1 = 0;
  float ax[4], ay[4], az[4];
#pragma unroll
  for (int k = 0; k < 4; ++k) {
    const float* p = xb + (size_t)(k * 64 + lane) * 3;
    ax[k] = p[0];
    ay[k] = p[1];
    az[k] = p[2];
  }
  for (int j0 = 0; j0 < NN; j0 += 256) {
    float bx[4] = {0}, by[4] = {0}, bz[4] = {0};
    const int jn = j0 + 256;
    if (jn < NN) {  // prefetch next chunk while ballots run on current
#pragma unroll
      for (int k = 0; k < 4; ++k) {
        const float* p = xb + (size_t)(jn + k * 64 + lane) * 3;
        bx[k] = p[0];
        by[k] = p[1];
        bz[k] = p[2];
      }
    }
#pragma unroll
    for (int k = 0; k < 4; ++k) {  // k-major preserves point order
      const int j = j0 + k * 64 + lane;
      const float nn_ = ax[k] * ax[k] + ay[k] * ay[k] + az[k] * az[k];
      const float dot0 = c0x * ax[k] + c0y * ay[k] + c0z * az[k];
      const float dot1 = c1x * ax[k] + c1y * ay[k] + c1z * az[k];
      const bool hit0 = (qq0 + nn_ - 2.0f * dot0) < R2;
      const bool hit1 = (qq1 + nn_ - 2.0f * dot1) < R2;
      const unsigned long long m0 = __ballot(hit0);
      const unsigned long long m1 = __ballot(hit1);
      if (hit0) {
        const int pos = cnt0 + (int)__popcll(m0 & ((1ull << lane) - 1ull));
        if (pos < NSAMPLE) sidx[wid][0][pos] = j;
      }
      if (hit1) {
        const int pos = cnt1 + (int)__popcll(m1 & ((1ull << lane) - 1ull));
        if (pos < NSAMPLE) sidx[wid][1][pos] = j;
      }
      cnt0 += (int)__popcll(m0);
      cnt1 += (int)__popcll(m1);
    }
    if (cnt0 >= NSAMPLE && cnt1 >= NSAMPLE) break;
#pragma unroll
    for (int k = 0; k < 4; ++k) {
      ax[k] = bx[k];
      ay[k] = by[k];
      az[k] = bz[k];
    }
  }
  // Pad with first hit (center always hits itself -> cnt >= 1). Same-wave DS
  // ops are in-order: reads below see the scatter writes without a barrier.
  const int v0 = sidx[wid][0][lane < cnt0 ? lane : 0];
  out[OFF_IDX + (size_t)q0 * NSAMPLE + lane] = (float)v0;
  const int v1 = sidx[wid][1][lane < cnt1 ? lane : 0];
  out[OFF_IDX + (size_t)q1 * NSAMPLE + lane] = (float)v1;
}

// ---------------------------------------------------------------------------
// Kernel 2: barrier-free MFMA MLP (R12 dataflow) in a single ping-pong LDS
// buffer per wave. NO cross-query gather prefetch (R10/R13: any >=32-reg
// carried gather spills — arch-VGPR headroom above this working set is ~0
// because weight fragments occupy the unified file's AGPR side).
// ---------------------------------------------------------------------------
__global__ __launch_bounds__(128, 2) void mlp_mfma(
    const float* __restrict__ xyz, const float* __restrict__ features,
    const int* __restrict__ inds,
    const float* __restrict__ w0, const float* __restrict__ s0,
    const float* __restrict__ t0, const float* __restrict__ w1,
    const float* __restrict__ s1, const float* __restrict__ t1,
    const float* __restrict__ w2, const float* __restrict__ s2,
    const float* __restrict__ t2, float* __restrict__ out) {
  __shared__ _Float16 sm[2 * XW];  // 22528 B -> 7 blocks/CU, 14 waves/CU
  const int tid = threadIdx.x;
  const int w = tid >> 6;
  const int l = tid & 63;
  const int l31 = l & 31;
  const int h5 = l >> 5;
  const int koff = h5 * 8;  // fragment k-offset in halves

  half8 b0f[2][5], b1f[2][4], b2f[4][4];

  // ---- phase A: stage + hoist W0', W1' ----
  {
    const int d = tid >> 1, hf = tid & 1;
    const float sd0 = s0[d], td0 = t0[d], sd1 = s1[d];
#pragma unroll
    for (int j = 0; j < 44; ++j) {
      const int c = hf * 44 + j;
      float v = 0.0f;
      if (c < 64) v = w0[(3 + c) * 64 + d] * sd0;        // feature channels
      else if (c < 67) v = w0[(c - 64) * 64 + d] * sd0;  // xyz channels
      else if (c == 67) v = td0;                         // bias channel
      sm[WT0_S + d * P0 + c] = (_Float16)v;
    }
#pragma unroll
    for (int j = 0; j < 32; ++j) {
      const int c = hf * 32 + j;
      sm[WT1_S + d * 72 + c] = (_Float16)(w1[c * 64 + d] * sd1);
    }
  }
  __syncthreads();
#pragma unroll
  for (int nt = 0; nt < 2; ++nt)
#pragma unroll
    for (int ks = 0; ks < 5; ++ks)
      b0f[nt][ks] =
          *(const half8*)&sm[WT0_S + (nt * 32 + l31) * P0 + ks * 16 + koff];
#pragma unroll
  for (int nt = 0; nt < 2; ++nt)
#pragma unroll
    for (int ks = 0; ks < 4; ++ks)
      b1f[nt][ks] =
          *(const half8*)&sm[WT1_S + (nt * 32 + l31) * 72 + ks * 16 + koff];
  __syncthreads();

  // ---- phase B: stage + hoist W2' ----
  {
    const int ch = tid;  // 0..127
    const float sch = s2[ch];
#pragma unroll
    for (int c = 0; c < 64; ++c)
      sm[WT2_S + ch * 72 + c] = (_Float16)(w2[c * 128 + ch] * sch);
  }
  __syncthreads();
#pragma unroll
  for (int ct = 0; ct < 4; ++ct)
#pragma unroll
    for (int ks = 0; ks < 4; ++ks)
      b2f[ct][ks] =
          *(const half8*)&sm[WT2_S + (ct * 32 + l31) * 72 + ks * 16 + koff];
  const float t1v0 = t1[l31];
  const float t1v1 = t1[32 + l31];
  float t2v[4];
#pragma unroll
  for (int ct = 0; ct < 4; ++ct) t2v[ct] = t2[ct * 32 + l31];
  __syncthreads();  // all fragment reads done before slices overwrite region

  _Float16* xbuf = sm + w * XW;  // single ping-pong buffer for X/H0/H1
  // zero X K-pad halves 72..79 once (H0/H1 writes touch cols <=63 only,
  // X staging touches cols <=71 -> pad stays zero across queries)
  {
    half8 z = {};
    *(half8*)&xbuf[l * P0 + 72] = z;
  }

  const int wq0 = (blockIdx.x * 2 + w) * QPW;
  const int b = wq0 >> 11;  // QPW | 2048 -> all queries share one batch
  const float* xb = xyz + (size_t)b * NN * 3;
  const float* fbase = features + (size_t)b * NN * CIN;

  // ---- prologue: first query's idx / center / pp ----
  int myidx = (int)out[OFF_IDX + (size_t)wq0 * NSAMPLE + l];
  int indv = inds[wq0];
  float cx = xb[indv * 3 + 0], cy = xb[indv * 3 + 1], cz = xb[indv * 3 + 2];
  float ppx = xb[myidx * 3 + 0], ppy = xb[myidx * 3 + 1],
        ppz = xb[myidx * 3 + 2];

#pragma unroll 1
  for (int qi = 0; qi < QPW; ++qi) {
    const int q = wq0 + qi;
    const int nq = (qi + 1 < QPW) ? q + 1 : q;  // clamp: redundant reload ok

    // ---- grouped coalesced feature gather (16 lines/instr; R12) ----
    float4 g[16];
#pragma unroll
    for (int i = 0; i < 16; ++i) {
      const int s = (l >> 2) + 16 * (i & 3);
      const int c = (l & 3) + 4 * (i >> 2);
      const int sidx = __shfl(myidx, s, 64);
      g[i] = *(const float4*)(fbase + (size_t)sidx * CIN + 4 * c);
    }
    // issue next query's idx + inds loads (consumed after L0 / at rotate)
    const float fni = out[OFF_IDX + (size_t)nq * NSAMPLE + l];
    const int nindv = inds[nq];

    // ---- stage X (overwrites previous query's H1; h1a reads done) ----
#pragma unroll
    for (int i = 0; i < 16; ++i) {
      const int s = (l >> 2) + 16 * (i & 3);
      const int c = (l & 3) + 4 * (i >> 2);
      union {
        half4 v;
        f16x2 p[2];
      } hv;
      hv.p[0] = __builtin_amdgcn_cvt_pkrtz(g[i].x, g[i].y);
      hv.p[1] = __builtin_amdgcn_cvt_pkrtz(g[i].z, g[i].w);
      *(half4*)&xbuf[s * P0 + 4 * c] = hv.v;
    }
    {
      union {
        half8 v;
        f16x2 p[4];
      } xv;
      xv.p[0] =
          __builtin_amdgcn_cvt_pkrtz((ppx - cx) * 5.0f, (ppy - cy) * 5.0f);
      xv.p[1] = __builtin_amdgcn_cvt_pkrtz((ppz - cz) * 5.0f, 1.0f);  // bias
      xv.p[2] = __builtin_amdgcn_cvt_pkrtz(0.0f, 0.0f);
      xv.p[3] = __builtin_amdgcn_cvt_pkrtz(0.0f, 0.0f);
      *(half8*)&xbuf[l * P0 + 64] = xv.v;
    }

    // ---- L0: read all of X into xa, then H0 overwrites cols 0..63 ----
    {
      half8 xa[2][5];
#pragma unroll
      for (int st = 0; st < 2; ++st)
#pragma unroll
        for (int ks = 0; ks < 5; ++ks)
          xa[st][ks] =
              *(const half8*)&xbuf[(st * 32 + l31) * P0 + ks * 16 + koff];
#pragma unroll
      for (int nt = 0; nt < 2; ++nt)
#pragma unroll
        for (int st = 0; st < 2; ++st) {
          floatx16 acc;
#pragma unroll
          for (int i = 0; i < 16; ++i) acc[i] = 0.0f;
#pragma unroll
          for (int ks = 0; ks < 5; ++ks)
            acc = __builtin_amdgcn_mfma_f32_32x32x16_f16(xa[st][ks],
                                                         b0f[nt][ks], acc,
                                                         0, 0, 0);
#pragma unroll
          for (int reg = 0; reg < 16; ++reg) {
            const int row = st * 32 + (reg & 3) + 8 * (reg >> 2) + 4 * h5;
            xbuf[row * P0 + nt * 32 + l31] = (_Float16)fmaxf(acc[reg], 0.0f);
          }
        }
    }

    // ---- issue next query's center + pp loads (covered by L1+L2) ----
    const int nidxs = (int)fni;
    const float ncx = xb[nindv * 3 + 0];
    const float ncy = xb[nindv * 3 + 1];
    const float ncz = xb[nindv * 3 + 2];
    const float nppx = xb[nidxs * 3 + 0];
    const float nppy = xb[nidxs * 3 + 1];
    const float nppz = xb[nidxs * 3 + 2];

    // ---- L1: read H0 into ha, then H1 overwrites same region ----
    {
      half8 ha[2][4];
#pragma unroll
      for (int st = 0; st < 2; ++st)
#pragma unroll
        for (int ks = 0; ks < 4; ++ks)
          ha[st][ks] =
              *(const half8*)&xbuf[(st * 32 + l31) * P0 + ks * 16 + koff];
#pragma unroll
      for (int nt = 0; nt < 2; ++nt) {
        const float tt = nt ? t1v1 : t1v0;
#pragma unroll
        for (int st = 0; st < 2; ++st) {
          floatx16 acc;
#pragma unroll
          for (int i = 0; i < 16; ++i) acc[i] = 0.0f;
#pragma unroll
          for (int ks = 0; ks < 4; ++ks)
            acc = __builtin_amdgcn_mfma_f32_32x32x16_f16(ha[st][ks],
                                                         b1f[nt][ks], acc,
                                                         0, 0, 0);
#pragma unroll
          for (int reg = 0; reg < 16; ++reg) {
            const int row = st * 32 + (reg & 3) + 8 * (reg >> 2) + 4 * h5;
            xbuf[row * P0 + nt * 32 + l31] =
                (_Float16)fmaxf(acc[reg] + tt, 0.0f);
          }
        }
      }
    }

    // ---- L2: Y = H1 @ W2' (lane owns d2 column), fused maxpool ----
    {
      half8 h1a[2][4];
#pragma unroll
      for (int st = 0; st < 2; ++st)
#pragma unroll
        for (int ks = 0; ks < 4; ++ks)
          h1a[st][ks] =
              *(const half8*)&xbuf[(st * 32 + l31) * P0 + ks * 16 + koff];
#pragma unroll
      for (int ct = 0; ct < 4; ++ct) {
        floatx16 aA, aB;
#pragma unroll
        for (int i = 0; i < 16; ++i) {
          aA[i] = 0.0f;
          aB[i] = 0.0f;
        }
#pragma unroll
        for (int ks = 0; ks < 4; ++ks) {
          aA = __builtin_amdgcn_mfma_f32_32x32x16_f16(h1a[0][ks], b2f[ct][ks],
                                                      aA, 0, 0, 0);
          aB = __builtin_amdgcn_mfma_f32_32x32x16_f16(h1a[1][ks], b2f[ct][ks],
                                                      aB, 0, 0, 0);
        }
        float m = fmaxf(aA[0], aB[0]);
#pragma unroll
        for (int i = 1; i < 16; ++i) m = fmaxf(m, fmaxf(aA[i], aB[i]));
        float v = fmaxf(m + t2v[ct], 0.0f);  // relu(max+t) == max(relu(+t))
        v = fmaxf(v, __shfl_xor(v, 32, 64));  // merge complementary row halves
        if (l < 32) out[OFF_FEAT + (size_t)q * 128 + ct * 32 + l] = v;
      }
    }

    // ---- rotate pipeline registers ----
    myidx = nidxs;
    cx = ncx; cy = ncy; cz = ncz;
    ppx = nppx; ppy = nppy; ppz = nppz;
  }
}

extern "C" void kernel_launch(void* const* d_in, const int* in_sizes, int n_in,
                              void* d_out, int out_size, void* d_ws,
                              size_t ws_size, hipStream_t stream) {
  const float* xyz = (const float*)d_in[0];
  const float* features = (const float*)d_in[1];
  const int* inds = (const int*)d_in[2];
  const float* w0 = (const float*)d_in[3];
  const float* s0 = (const float*)d_in[4];
  const float* t0 = (const float*)d_in[5];
  const float* w1 = (const float*)d_in[6];
  const float* s1 = (const float*)d_in[7];
  const float* t1 = (const float*)d_in[8];
  const float* w2 = (const float*)d_in[9];
  const float* s2 = (const float*)d_in[10];
  const float* t2 = (const float*)d_in[11];
  float* out = (float*)d_out;

  const int nquery = BB * NPOINT;  // 16384
  // ballq: 2 queries per wave -> 8192 waves -> 2048 blocks
  ballq_kernel<<<nquery / 8, 256, 0, stream>>>(xyz, inds, out);
  // mlp: 2 waves/block * QPW queries each -> 2048 blocks (7 resident/CU)
  mlp_mfma<<<nquery / (2 * QPW), 128, 0, stream>>>(
      xyz, features, inds, w0, s0, t0, w1, s1, t1, w2, s2, t2, out);
}